// Round 4
// baseline (306.148 us; speedup 1.0000x reference)
//
#include <hip/hip_runtime.h>
#include <hip/hip_bf16.h>

#define PREFIX_N 20000
#define LEAF_N   50000
#define CH_N     100000
#define CCOL     256
#define GK       2048
#define GM       50000
#define BM       64
#define BKT      256                    /* K-elements per step */
#define NST      (GK / BKT)             /* 8 steps */
#define TILES    ((GM + BM - 1) / BM)   /* 782 */
#define COPYB    256
#define IT_TOTAL (70000 * 64)           /* float4 items to copy */

typedef float  f32x4v __attribute__((ext_vector_type(4)));
typedef __bf16 bf16x8 __attribute__((ext_vector_type(8)));
typedef short  s16x8  __attribute__((ext_vector_type(8)));

static __device__ __forceinline__ unsigned pk2(float a, float b) {
  __hip_bfloat16 ha = __float2bfloat16(a);
  __hip_bfloat16 hb = __float2bfloat16(b);
  unsigned short sa = __builtin_bit_cast(unsigned short, ha);
  unsigned short sb = __builtin_bit_cast(unsigned short, hb);
  return (unsigned)sa | ((unsigned)sb << 16);
}
static __device__ __forceinline__ uint4 pack8(const float4& x, const float4& y) {
  uint4 r;
  r.x = pk2(x.x, x.y); r.y = pk2(x.z, x.w);
  r.z = pk2(y.x, y.y); r.w = pk2(y.z, y.w);
  return r;
}

#define GLDS16(g, l) __builtin_amdgcn_global_load_lds(                      \
    (const __attribute__((address_space(1))) void*)(g),                     \
    (__attribute__((address_space(3))) void*)(l), 16, 0, 0)

// ---- prep: W fp32->bf16 (blocks 0..255) + leaf count (blocks 256..646) ---
__global__ __launch_bounds__(256) void prep_kernel(const float* __restrict__ W,
                                                   unsigned short* __restrict__ Wb,
                                                   const int* __restrict__ ch,
                                                   int* __restrict__ cnt) {
  if (blockIdx.x < 256) {
    int i = blockIdx.x * 256 + threadIdx.x;
    float4 a = ((const float4*)W)[i * 2];
    float4 b = ((const float4*)W)[i * 2 + 1];
    *(uint4*)&Wb[i * 8] = pack8(a, b);
  } else {
    int blk = blockIdx.x - 256;
    int gi = blk * 256 + threadIdx.x;
    int lm = (gi < CH_N && ch[gi] < 0) ? 1 : 0;
    unsigned long long mask = __ballot(lm);
    __shared__ int wsum[4];
    int lane = threadIdx.x & 63, w = threadIdx.x >> 6;
    if (lane == 0) wsum[w] = __popcll(mask);
    __syncthreads();
    if (threadIdx.x == 0) cnt[blk] = wsum[0] + wsum[1] + wsum[2] + wsum[3];
  }
}

__global__ __launch_bounds__(512) void scan_blocks(const int* __restrict__ cnt,
                                                   int* __restrict__ boff, int nb) {
  __shared__ int s[512];
  int t = threadIdx.x;
  int v = (t < nb) ? cnt[t] : 0;
  s[t] = v;
  __syncthreads();
  for (int d = 1; d < 512; d <<= 1) {
    int add = (t >= d) ? s[t - d] : 0;
    __syncthreads();
    s[t] += add;
    __syncthreads();
  }
  if (t < nb) boff[t] = s[t] - v;
}

__global__ __launch_bounds__(256) void rank_kernel(const int* __restrict__ ch,
                                                   const int* __restrict__ boff, int n,
                                                   int* __restrict__ rowof,
                                                   int* __restrict__ leafof) {
  int gi = blockIdx.x * 256 + threadIdx.x;
  int lane = threadIdx.x & 63, w = threadIdx.x >> 6;
  int lm = (gi < n && ch[gi] < 0) ? 1 : 0;
  unsigned long long mask = __ballot(lm);
  int lrank = __popcll(mask & ((1ull << lane) - 1ull));
  __shared__ int wcnt[4];
  if (lane == 63) wcnt[w] = lrank + lm;
  __syncthreads();
  int woff = 0;
  for (int i = 0; i < w; ++i) woff += wcnt[i];
  if (gi < n) {
    int rl = boff[blockIdx.x] + woff + lrank;
    if (lm) leafof[rl] = gi;
    else    rowof[gi - rl] = gi;
  }
}

// ---- main: GEMM tiles (blocks < TILES) + grid-stride copies -------------
// GEMM: BM=64, BN=256(full), BK=256; 256 thr = 4 waves (N-split).
// A staged fp32 via global_load_lds (1 glds = one 1KB row chunk, XOR-swizzled
// source), dbuf LDS, counted-vmcnt pipeline, raw barriers (no vmcnt(0) drain
// in the loop). B read directly from L2/L3-resident bf16 W.
__global__ __launch_bounds__(256) void main_kernel(const float* __restrict__ x,
                                                   const float* __restrict__ A,
                                                   const unsigned short* __restrict__ Wb,
                                                   const int* __restrict__ rowof,
                                                   const int* __restrict__ leafof,
                                                   float* __restrict__ out) {
  __shared__ float Al[2][BM][BKT];     // 2 x 64KB
  __shared__ int tgt[BM];

  const int tid  = threadIdx.x;
  const int lane = tid & 63;
  const int w    = tid >> 6;

  if (blockIdx.x >= TILES) {                      // ---- copy path ----
    int cb = blockIdx.x - TILES;
    const float4* xv = (const float4*)x;
    float4* ov = (float4*)out;
    for (int base = cb * 1024; base < IT_TOTAL; base += COPYB * 1024) {
#pragma unroll
      for (int u = 0; u < 4; ++u) {
        int it = base + u * 256 + tid;
        if (it < IT_TOTAL) {
          int row = it >> 6, col = it & 63;
          int drow = (row < PREFIX_N) ? row
                                      : (PREFIX_N + leafof[row - PREFIX_N]);
          ov[(size_t)drow * 64 + col] = xv[(size_t)row * 64 + col];
        }
      }
    }
    return;
  }

  // ---- GEMM path ----
  const int tile = blockIdx.x;
  const int wn   = w;                  // wave's N-quadrant
  const int lr   = lane & 15, lq = lane >> 4;

  if (tid < BM) {
    int m = tile * BM + tid;
    tgt[tid] = (m < GM) ? (PREFIX_N + rowof[m]) : -1;
  }

  // per-lane swizzled source offsets (bytes): chunk = lane ^ (row&7)
  int swz[8];
#pragma unroll
  for (int j = 0; j < 8; ++j) swz[j] = (lane ^ j) << 4;

  // this wave's 16 A-row base pointers (clamped for tail tile)
  const char* arow[16];
#pragma unroll
  for (int i = 0; i < 16; ++i) {
    int gr = tile * BM + w * 16 + i;
    if (gr >= GM) gr = GM - 1;
    arow[i] = (const char*)(A + (size_t)gr * GK);
  }

  // B fragment base pointers (global; W is 1MB, L2/L3-resident)
  const unsigned short* bb[4];
#pragma unroll
  for (int fn = 0; fn < 4; ++fn)
    bb[fn] = Wb + (size_t)(wn * 64 + fn * 16 + lr) * GK + lq * 8;

  f32x4v acc[4][4] = {};

#define ISSUE_A(kt_, buf_)                                                   \
  { _Pragma("unroll") for (int i = 0; i < 16; ++i)                           \
      GLDS16(arow[i] + (size_t)(kt_) * 1024 + swz[i & 7],                    \
             (char*)&Al[(buf_)][w * 16 + i][0]); }

  ISSUE_A(0, 0);
  ISSUE_A(1, 1);

#pragma unroll 1
  for (int kt = 0; kt < NST; ++kt) {
    if (kt < NST - 1) { asm volatile("s_waitcnt vmcnt(16)" ::: "memory"); }
    else              { asm volatile("s_waitcnt vmcnt(0)"  ::: "memory"); }
    __builtin_amdgcn_sched_barrier(0);
    __builtin_amdgcn_s_barrier();
    __builtin_amdgcn_sched_barrier(0);

    const float* Ab = &Al[kt & 1][0][0];
#pragma unroll 2
    for (int ks = 0; ks < 8; ++ks) {
      s16x8 af[4], bf[4];
#pragma unroll
      for (int fm = 0; fm < 4; ++fm) {
        int row = fm * 16 + lr;
        int c0  = ks * 8 + lq * 2;
        int p0  = ((c0)     ^ (row & 7)) * 4;
        int p1  = ((c0 + 1) ^ (row & 7)) * 4;
        float4 u0 = *(const float4*)&Ab[row * BKT + p0];
        float4 u1 = *(const float4*)&Ab[row * BKT + p1];
        af[fm] = __builtin_bit_cast(s16x8, pack8(u0, u1));
      }
#pragma unroll
      for (int fn = 0; fn < 4; ++fn)
        bf[fn] = *(const s16x8*)&bb[fn][kt * BKT + ks * 32];
#pragma unroll
      for (int fm = 0; fm < 4; ++fm)
#pragma unroll
        for (int fn = 0; fn < 4; ++fn)
          acc[fm][fn] = __builtin_amdgcn_mfma_f32_16x16x32_bf16(
              __builtin_bit_cast(bf16x8, af[fm]),
              __builtin_bit_cast(bf16x8, bf[fn]),
              acc[fm][fn], 0, 0, 0);
    }

    __builtin_amdgcn_sched_barrier(0);
    __builtin_amdgcn_s_barrier();
    __builtin_amdgcn_sched_barrier(0);
    if (kt + 2 < NST) ISSUE_A(kt + 2, kt & 1);   // back into the buffer just read
  }
#undef ISSUE_A

  // ---- epilogue: scatter rows (C/D: col=lane&15, row=(lane>>4)*4+reg) ----
#pragma unroll
  for (int fm = 0; fm < 4; ++fm) {
    int mlb = fm * 16 + lq * 4;
    int t0 = tgt[mlb + 0], t1 = tgt[mlb + 1], t2 = tgt[mlb + 2], t3 = tgt[mlb + 3];
#pragma unroll
    for (int fn = 0; fn < 4; ++fn) {
      int col = wn * 64 + fn * 16 + lr;
      if (t0 >= 0) out[(size_t)t0 * CCOL + col] = acc[fm][fn][0];
      if (t1 >= 0) out[(size_t)t1 * CCOL + col] = acc[fm][fn][1];
      if (t2 >= 0) out[(size_t)t2 * CCOL + col] = acc[fm][fn][2];
      if (t3 >= 0) out[(size_t)t3 * CCOL + col] = acc[fm][fn][3];
    }
  }
}

extern "C" void kernel_launch(void* const* d_in, const int* in_sizes, int n_in,
                              void* d_out, int out_size, void* d_ws, size_t ws_size,
                              hipStream_t stream) {
  const float* x        = (const float*)d_in[0];
  const float* wts      = (const float*)d_in[1];   // (256,256,8) == row-major (256,2048)
  const int*   children = (const int*)d_in[2];
  float*       out      = (float*)d_out;

  int* wsp    = (int*)d_ws;
  int* cnt    = wsp;                 // 391
  int* boff   = wsp + 512;           // 391
  int* rowof  = wsp + 1024;          // 50000
  int* leafof = wsp + 1024 + GM;     // 50000
  unsigned short* Wb = (unsigned short*)((char*)d_ws + (1 << 20));  // 1 MB bf16 W

  const int nb = (CH_N + 255) / 256;   // 391

  prep_kernel<<<256 + nb, 256, 0, stream>>>(wts, Wb, children, cnt);
  scan_blocks<<<1, 512, 0, stream>>>(cnt, boff, nb);
  rank_kernel<<<nb, 256, 0, stream>>>(children, boff, CH_N, rowof, leafof);

  const float* A = x + (size_t)(PREFIX_N + LEAF_N) * CCOL;
  main_kernel<<<TILES + COPYB, 256, 0, stream>>>(x, A, Wb, rowof, leafof, out);
}

// Round 5
// 207.079 us; speedup vs baseline: 1.4784x; 1.4784x over previous
//
#include <hip/hip_runtime.h>
#include <hip/hip_bf16.h>

#define PREFIX_N 20000
#define LEAF_N   50000
#define CH_N     100000
#define CCOL     256
#define GK       2048
#define GM       50000
#define BM       64
#define BKF      128                    /* K floats per step */
#define NST      (GK / BKF)             /* 16 steps */
#define TILES    ((GM + BM - 1) / BM)   /* 782 */
#define NCOPYB   512
#define COPYROWS 70000

typedef float  f32x4v __attribute__((ext_vector_type(4)));
typedef __bf16 bf16x8 __attribute__((ext_vector_type(8)));
typedef short  s16x8  __attribute__((ext_vector_type(8)));

static __device__ __forceinline__ unsigned pk2(float a, float b) {
  __hip_bfloat16 ha = __float2bfloat16(a);
  __hip_bfloat16 hb = __float2bfloat16(b);
  unsigned short sa = __builtin_bit_cast(unsigned short, ha);
  unsigned short sb = __builtin_bit_cast(unsigned short, hb);
  return (unsigned)sa | ((unsigned)sb << 16);
}
static __device__ __forceinline__ uint4 pack8(const float4& x, const float4& y) {
  uint4 r;
  r.x = pk2(x.x, x.y); r.y = pk2(x.z, x.w);
  r.z = pk2(y.x, y.y); r.w = pk2(y.z, y.w);
  return r;
}

#define GLDS16(g, l) __builtin_amdgcn_global_load_lds(                      \
    (const __attribute__((address_space(1))) void*)(g),                     \
    (__attribute__((address_space(3))) void*)(l), 16, 0, 0)

// ---- prep: W fp32->bf16 (blocks 0..255) + leaf count (blocks 256..646) ---
__global__ __launch_bounds__(256) void prep_kernel(const float* __restrict__ W,
                                                   unsigned short* __restrict__ Wb,
                                                   const int* __restrict__ ch,
                                                   int* __restrict__ cnt) {
  if (blockIdx.x < 256) {
    int i = blockIdx.x * 256 + threadIdx.x;
    float4 a = ((const float4*)W)[i * 2];
    float4 b = ((const float4*)W)[i * 2 + 1];
    *(uint4*)&Wb[i * 8] = pack8(a, b);
  } else {
    int blk = blockIdx.x - 256;
    int gi = blk * 256 + threadIdx.x;
    int lm = (gi < CH_N && ch[gi] < 0) ? 1 : 0;
    unsigned long long mask = __ballot(lm);
    __shared__ int wsum[4];
    int lane = threadIdx.x & 63, w = threadIdx.x >> 6;
    if (lane == 0) wsum[w] = __popcll(mask);
    __syncthreads();
    if (threadIdx.x == 0) cnt[blk] = wsum[0] + wsum[1] + wsum[2] + wsum[3];
  }
}

__global__ __launch_bounds__(512) void scan_blocks(const int* __restrict__ cnt,
                                                   int* __restrict__ boff, int nb) {
  __shared__ int s[512];
  int t = threadIdx.x;
  int v = (t < nb) ? cnt[t] : 0;
  s[t] = v;
  __syncthreads();
  for (int d = 1; d < 512; d <<= 1) {
    int add = (t >= d) ? s[t - d] : 0;
    __syncthreads();
    s[t] += add;
    __syncthreads();
  }
  if (t < nb) boff[t] = s[t] - v;
}

__global__ __launch_bounds__(256) void rank_kernel(const int* __restrict__ ch,
                                                   const int* __restrict__ boff, int n,
                                                   int* __restrict__ rowof,
                                                   int* __restrict__ leafof) {
  int gi = blockIdx.x * 256 + threadIdx.x;
  int lane = threadIdx.x & 63, w = threadIdx.x >> 6;
  int lm = (gi < n && ch[gi] < 0) ? 1 : 0;
  unsigned long long mask = __ballot(lm);
  int lrank = __popcll(mask & ((1ull << lane) - 1ull));
  __shared__ int wcnt[4];
  if (lane == 63) wcnt[w] = lrank + lm;
  __syncthreads();
  int woff = 0;
  for (int i = 0; i < w; ++i) woff += wcnt[i];
  if (gi < n) {
    int rl = boff[blockIdx.x] + woff + lrank;
    if (lm) leafof[rl] = gi;
    else    rowof[gi - rl] = gi;
  }
}

// ---- main: GEMM tiles (blocks < TILES) + grid-stride row copies ----------
// GEMM: BM=64, BN=256(full), BK=128; 256 thr = 4 waves (N-split), 2 blk/CU.
// A staged fp32 by global_load_lds (512B/row bursts, XOR-swizzled source +
// swizzled read); dbuf; counted vmcnt(8) pipeline, raw barriers; B direct
// from L2-resident bf16 W; cvt to bf16 at fragment read.
__global__ __launch_bounds__(256, 2) void main_kernel(const float* __restrict__ x,
                                                      const float* __restrict__ A,
                                                      const unsigned short* __restrict__ Wb,
                                                      const int* __restrict__ rowof,
                                                      const int* __restrict__ leafof,
                                                      float* __restrict__ out) {
  __shared__ float Al[2][BM][BKF];     // 2 x 32KB
  __shared__ int tgt[BM];

  const int tid  = threadIdx.x;
  const int lane = tid & 63;
  const int w    = tid >> 6;

  if (blockIdx.x >= TILES) {                      // ---- copy path ----
    int cb = blockIdx.x - TILES;
    for (int r0 = cb * 4; r0 < COPYROWS; r0 += NCOPYB * 4) {
      int j = r0 + w;
      if (j >= COPYROWS) break;
      const float* src;
      float* dst;
      if (j < PREFIX_N) {
        src = x + (size_t)j * CCOL;
        dst = out + (size_t)j * CCOL;
      } else {
        int r = j - PREFIX_N;
        src = x + (size_t)(PREFIX_N + r) * CCOL;
        dst = out + (size_t)(PREFIX_N + leafof[r]) * CCOL;
      }
      ((float4*)dst)[lane] = ((const float4*)src)[lane];
    }
    return;
  }

  // ---- GEMM path ----
  const int tile = blockIdx.x;
  const int wn   = w;                  // wave's N-quadrant
  const int lr   = lane & 15, lq = lane >> 4;

  if (tid < BM) {
    int m = tile * BM + tid;
    tgt[tid] = (m < GM) ? (PREFIX_N + rowof[m]) : -1;
  }

  // glds i covers rows w*16+2i (+1 for lanes>=32); source chunk pre-swizzled
  const float* asrc[8];
  int myrow = w * 16 + (lane >> 5);
#pragma unroll
  for (int i = 0; i < 8; ++i) {
    int r  = myrow + 2 * i;            // this lane's global A-row for glds i
    int gr = tile * BM + r;
    if (gr >= GM) gr = GM - 1;         // clamp (epilogue predicated)
    int chunk = (lane & 31) ^ (r & 7); // inverse swizzle on SOURCE
    asrc[i] = A + (size_t)gr * GK + chunk * 4;
  }

  // B fragment base pointers (global; Wb 1MB, L2-resident)
  const unsigned short* bb[4];
#pragma unroll
  for (int fn = 0; fn < 4; ++fn)
    bb[fn] = Wb + (size_t)(wn * 64 + fn * 16 + lr) * GK + lq * 8;

  f32x4v acc[4][4] = {};

#define ISSUE_A(kt_, buf_)                                                   \
  { _Pragma("unroll") for (int i = 0; i < 8; ++i)                            \
      GLDS16(asrc[i] + (kt_) * BKF, (char*)&Al[(buf_)][w * 16 + 2 * i][0]); }

  ISSUE_A(0, 0);
  ISSUE_A(1, 1);

#pragma unroll 1
  for (int kt = 0; kt < NST; ++kt) {
    if (kt < NST - 1) { asm volatile("s_waitcnt vmcnt(8)" ::: "memory"); }
    else              { asm volatile("s_waitcnt vmcnt(0)" ::: "memory"); }
    __builtin_amdgcn_s_barrier();      // buf kt fully staged (all waves)

    const float* Ab = &Al[kt & 1][0][0];
#pragma unroll
    for (int ks = 0; ks < 4; ++ks) {
      s16x8 af[4], bf[4];
#pragma unroll
      for (int fm = 0; fm < 4; ++fm) {
        int row = fm * 16 + lr;
        int e   = ks * 8 + lq * 2;
        int p0  = ((e)     ^ (row & 7)) << 2;   // swizzled read
        int p1  = ((e + 1) ^ (row & 7)) << 2;
        float4 u0 = *(const float4*)&Ab[row * BKF + p0];
        float4 u1 = *(const float4*)&Ab[row * BKF + p1];
        af[fm] = __builtin_bit_cast(s16x8, pack8(u0, u1));
      }
#pragma unroll
      for (int fn = 0; fn < 4; ++fn)
        bf[fn] = *(const s16x8*)&bb[fn][kt * BKF + ks * 32];
#pragma unroll
      for (int fm = 0; fm < 4; ++fm)
#pragma unroll
        for (int fn = 0; fn < 4; ++fn)
          acc[fm][fn] = __builtin_amdgcn_mfma_f32_16x16x32_bf16(
              __builtin_bit_cast(bf16x8, af[fm]),
              __builtin_bit_cast(bf16x8, bf[fn]),
              acc[fm][fn], 0, 0, 0);
    }

    asm volatile("s_waitcnt lgkmcnt(0)" ::: "memory");  // ds_reads of buf kt done
    __builtin_amdgcn_s_barrier();                       // safe to overwrite
    if (kt + 2 < NST) ISSUE_A(kt + 2, kt & 1);          // refill just-read buffer
  }
#undef ISSUE_A

  // ---- epilogue: scatter rows (C/D: col=lane&15, row=(lane>>4)*4+reg) ----
#pragma unroll
  for (int fm = 0; fm < 4; ++fm) {
    int mlb = fm * 16 + lq * 4;
    int t0 = tgt[mlb + 0], t1 = tgt[mlb + 1], t2 = tgt[mlb + 2], t3 = tgt[mlb + 3];
#pragma unroll
    for (int fn = 0; fn < 4; ++fn) {
      int col = wn * 64 + fn * 16 + lr;
      if (t0 >= 0) out[(size_t)t0 * CCOL + col] = acc[fm][fn][0];
      if (t1 >= 0) out[(size_t)t1 * CCOL + col] = acc[fm][fn][1];
      if (t2 >= 0) out[(size_t)t2 * CCOL + col] = acc[fm][fn][2];
      if (t3 >= 0) out[(size_t)t3 * CCOL + col] = acc[fm][fn][3];
    }
  }
}

extern "C" void kernel_launch(void* const* d_in, const int* in_sizes, int n_in,
                              void* d_out, int out_size, void* d_ws, size_t ws_size,
                              hipStream_t stream) {
  const float* x        = (const float*)d_in[0];
  const float* wts      = (const float*)d_in[1];   // (256,256,8) == row-major (256,2048)
  const int*   children = (const int*)d_in[2];
  float*       out      = (float*)d_out;

  int* wsp    = (int*)d_ws;
  int* cnt    = wsp;                 // 391
  int* boff   = wsp + 512;           // 391
  int* rowof  = wsp + 1024;          // 50000
  int* leafof = wsp + 1024 + GM;     // 50000
  unsigned short* Wb = (unsigned short*)((char*)d_ws + (1 << 20));  // 1 MB bf16 W

  const int nb = (CH_N + 255) / 256;   // 391

  prep_kernel<<<256 + nb, 256, 0, stream>>>(wts, Wb, children, cnt);
  scan_blocks<<<1, 512, 0, stream>>>(cnt, boff, nb);
  rank_kernel<<<nb, 256, 0, stream>>>(children, boff, CH_N, rowof, leafof);

  const float* A = x + (size_t)(PREFIX_N + LEAF_N) * CCOL;
  main_kernel<<<TILES + NCOPYB, 256, 0, stream>>>(x, A, Wb, rowof, leafof, out);
}

// Round 6
// 202.712 us; speedup vs baseline: 1.5103x; 1.0215x over previous
//
#include <hip/hip_runtime.h>
#include <hip/hip_bf16.h>

#define PREFIX_N 20000
#define LEAF_N   50000
#define CH_N     100000
#define CCOL     256
#define GK       2048
#define GM       50000
#define BM       64
#define BKF      128                    /* K floats per step */
#define NST      (GK / BKF)             /* 16 steps */
#define TILES    ((GM + BM - 1) / BM)   /* 782 */
#define NCOPYB   512
#define COPYROWS 70000

typedef float  f32x4v __attribute__((ext_vector_type(4)));
typedef __bf16 bf16x8 __attribute__((ext_vector_type(8)));
typedef short  s16x8  __attribute__((ext_vector_type(8)));

static __device__ __forceinline__ unsigned pk2(float a, float b) {
  __hip_bfloat16 ha = __float2bfloat16(a);
  __hip_bfloat16 hb = __float2bfloat16(b);
  unsigned short sa = __builtin_bit_cast(unsigned short, ha);
  unsigned short sb = __builtin_bit_cast(unsigned short, hb);
  return (unsigned)sa | ((unsigned)sb << 16);
}
static __device__ __forceinline__ uint4 pack8(const float4& x, const float4& y) {
  uint4 r;
  r.x = pk2(x.x, x.y); r.y = pk2(x.z, x.w);
  r.z = pk2(y.x, y.y); r.w = pk2(y.z, y.w);
  return r;
}

#define GLDS16(g, l) __builtin_amdgcn_global_load_lds(                      \
    (const __attribute__((address_space(1))) void*)(g),                     \
    (__attribute__((address_space(3))) void*)(l), 16, 0, 0)

// ---- prep: W fp32->bf16 (blocks 0..255) + leaf count (blocks 256..646) ---
__global__ __launch_bounds__(256) void prep_kernel(const float* __restrict__ W,
                                                   unsigned short* __restrict__ Wb,
                                                   const int* __restrict__ ch,
                                                   int* __restrict__ cnt) {
  if (blockIdx.x < 256) {
    int i = blockIdx.x * 256 + threadIdx.x;
    float4 a = ((const float4*)W)[i * 2];
    float4 b = ((const float4*)W)[i * 2 + 1];
    *(uint4*)&Wb[i * 8] = pack8(a, b);
  } else {
    int blk = blockIdx.x - 256;
    int gi = blk * 256 + threadIdx.x;
    int lm = (gi < CH_N && ch[gi] < 0) ? 1 : 0;
    unsigned long long mask = __ballot(lm);
    __shared__ int wsum[4];
    int lane = threadIdx.x & 63, w = threadIdx.x >> 6;
    if (lane == 0) wsum[w] = __popcll(mask);
    __syncthreads();
    if (threadIdx.x == 0) cnt[blk] = wsum[0] + wsum[1] + wsum[2] + wsum[3];
  }
}

__global__ __launch_bounds__(512) void scan_blocks(const int* __restrict__ cnt,
                                                   int* __restrict__ boff, int nb) {
  __shared__ int s[512];
  int t = threadIdx.x;
  int v = (t < nb) ? cnt[t] : 0;
  s[t] = v;
  __syncthreads();
  for (int d = 1; d < 512; d <<= 1) {
    int add = (t >= d) ? s[t - d] : 0;
    __syncthreads();
    s[t] += add;
    __syncthreads();
  }
  if (t < nb) boff[t] = s[t] - v;
}

__global__ __launch_bounds__(256) void rank_kernel(const int* __restrict__ ch,
                                                   const int* __restrict__ boff, int n,
                                                   int* __restrict__ rowof,
                                                   int* __restrict__ leafof) {
  int gi = blockIdx.x * 256 + threadIdx.x;
  int lane = threadIdx.x & 63, w = threadIdx.x >> 6;
  int lm = (gi < n && ch[gi] < 0) ? 1 : 0;
  unsigned long long mask = __ballot(lm);
  int lrank = __popcll(mask & ((1ull << lane) - 1ull));
  __shared__ int wcnt[4];
  if (lane == 63) wcnt[w] = lrank + lm;
  __syncthreads();
  int woff = 0;
  for (int i = 0; i < w; ++i) woff += wcnt[i];
  if (gi < n) {
    int rl = boff[blockIdx.x] + woff + lrank;
    if (lm) leafof[rl] = gi;
    else    rowof[gi - rl] = gi;
  }
}

// ---- main: GEMM tiles (blocks < TILES) + grid-stride row copies ----------
// GEMM identical to round-5 EXCEPT per-block K-phase rotation: block b
// processes K-chunks in order (phase+kt) mod 16, phase = b & 15, so the
// chip's blocks cover all 8KB-offset classes simultaneously (breaks HBM
// channel aliasing of the 8KB-strided A stream).
__global__ __launch_bounds__(256, 2) void main_kernel(const float* __restrict__ x,
                                                      const float* __restrict__ A,
                                                      const unsigned short* __restrict__ Wb,
                                                      const int* __restrict__ rowof,
                                                      const int* __restrict__ leafof,
                                                      float* __restrict__ out) {
  __shared__ float Al[2][BM][BKF];     // 2 x 32KB
  __shared__ int tgt[BM];

  const int tid  = threadIdx.x;
  const int lane = tid & 63;
  const int w    = tid >> 6;

  if (blockIdx.x >= TILES) {                      // ---- copy path ----
    int cb = blockIdx.x - TILES;
    for (int r0 = cb * 4; r0 < COPYROWS; r0 += NCOPYB * 4) {
      int j = r0 + w;
      if (j >= COPYROWS) break;
      const float* src;
      float* dst;
      if (j < PREFIX_N) {
        src = x + (size_t)j * CCOL;
        dst = out + (size_t)j * CCOL;
      } else {
        int r = j - PREFIX_N;
        src = x + (size_t)(PREFIX_N + r) * CCOL;
        dst = out + (size_t)(PREFIX_N + leafof[r]) * CCOL;
      }
      ((float4*)dst)[lane] = ((const float4*)src)[lane];
    }
    return;
  }

  // ---- GEMM path ----
  const int tile  = blockIdx.x;
  const int phase = tile & (NST - 1);
  const int wn    = w;                 // wave's N-quadrant
  const int lr    = lane & 15, lq = lane >> 4;

  if (tid < BM) {
    int m = tile * BM + tid;
    tgt[tid] = (m < GM) ? (PREFIX_N + rowof[m]) : -1;
  }

  // glds i covers rows w*16+2i (+1 for lanes>=32); source chunk pre-swizzled
  const float* asrc[8];
  int myrow = w * 16 + (lane >> 5);
#pragma unroll
  for (int i = 0; i < 8; ++i) {
    int r  = myrow + 2 * i;            // this lane's global A-row for glds i
    int gr = tile * BM + r;
    if (gr >= GM) gr = GM - 1;         // clamp (epilogue predicated)
    int chunk = (lane & 31) ^ (r & 7); // inverse swizzle on SOURCE
    asrc[i] = A + (size_t)gr * GK + chunk * 4;
  }

  // B fragment base pointers (global; Wb 1MB, L2-resident)
  const unsigned short* bb[4];
#pragma unroll
  for (int fn = 0; fn < 4; ++fn)
    bb[fn] = Wb + (size_t)(wn * 64 + fn * 16 + lr) * GK + lq * 8;

  f32x4v acc[4][4] = {};

#define ISSUE_A(kc_, buf_)                                                   \
  { _Pragma("unroll") for (int i = 0; i < 8; ++i)                            \
      GLDS16(asrc[i] + (kc_) * BKF, (char*)&Al[(buf_)][w * 16 + 2 * i][0]); }

  {
    int kc0 = phase;
    int kc1 = (phase + 1) & (NST - 1);
    ISSUE_A(kc0, 0);
    ISSUE_A(kc1, 1);
  }

#pragma unroll 1
  for (int kt = 0; kt < NST; ++kt) {
    int kc = phase + kt; if (kc >= NST) kc -= NST;   // rotated K-chunk
    if (kt < NST - 1) { asm volatile("s_waitcnt vmcnt(8)" ::: "memory"); }
    else              { asm volatile("s_waitcnt vmcnt(0)" ::: "memory"); }
    __builtin_amdgcn_s_barrier();      // buf kt fully staged (all waves)

    const float* Ab = &Al[kt & 1][0][0];
#pragma unroll
    for (int ks = 0; ks < 4; ++ks) {
      s16x8 af[4], bf[4];
#pragma unroll
      for (int fm = 0; fm < 4; ++fm) {
        int row = fm * 16 + lr;
        int e   = ks * 8 + lq * 2;
        int p0  = ((e)     ^ (row & 7)) << 2;   // swizzled read
        int p1  = ((e + 1) ^ (row & 7)) << 2;
        float4 u0 = *(const float4*)&Ab[row * BKF + p0];
        float4 u1 = *(const float4*)&Ab[row * BKF + p1];
        af[fm] = __builtin_bit_cast(s16x8, pack8(u0, u1));
      }
#pragma unroll
      for (int fn = 0; fn < 4; ++fn)
        bf[fn] = *(const s16x8*)&bb[fn][kc * BKF + ks * 32];
#pragma unroll
      for (int fm = 0; fm < 4; ++fm)
#pragma unroll
        for (int fn = 0; fn < 4; ++fn)
          acc[fm][fn] = __builtin_amdgcn_mfma_f32_16x16x32_bf16(
              __builtin_bit_cast(bf16x8, af[fm]),
              __builtin_bit_cast(bf16x8, bf[fn]),
              acc[fm][fn], 0, 0, 0);
    }

    asm volatile("s_waitcnt lgkmcnt(0)" ::: "memory");  // ds_reads of buf kt done
    __builtin_amdgcn_s_barrier();                       // safe to overwrite
    if (kt + 2 < NST) {
      int kc2 = phase + kt + 2; if (kc2 >= NST) kc2 -= NST;
      ISSUE_A(kc2, kt & 1);                             // refill just-read buffer
    }
  }
#undef ISSUE_A

  // ---- epilogue: scatter rows (C/D: col=lane&15, row=(lane>>4)*4+reg) ----
#pragma unroll
  for (int fm = 0; fm < 4; ++fm) {
    int mlb = fm * 16 + lq * 4;
    int t0 = tgt[mlb + 0], t1 = tgt[mlb + 1], t2 = tgt[mlb + 2], t3 = tgt[mlb + 3];
#pragma unroll
    for (int fn = 0; fn < 4; ++fn) {
      int col = wn * 64 + fn * 16 + lr;
      if (t0 >= 0) out[(size_t)t0 * CCOL + col] = acc[fm][fn][0];
      if (t1 >= 0) out[(size_t)t1 * CCOL + col] = acc[fm][fn][1];
      if (t2 >= 0) out[(size_t)t2 * CCOL + col] = acc[fm][fn][2];
      if (t3 >= 0) out[(size_t)t3 * CCOL + col] = acc[fm][fn][3];
    }
  }
}

extern "C" void kernel_launch(void* const* d_in, const int* in_sizes, int n_in,
                              void* d_out, int out_size, void* d_ws, size_t ws_size,
                              hipStream_t stream) {
  const float* x        = (const float*)d_in[0];
  const float* wts      = (const float*)d_in[1];   // (256,256,8) == row-major (256,2048)
  const int*   children = (const int*)d_in[2];
  float*       out      = (float*)d_out;

  int* wsp    = (int*)d_ws;
  int* cnt    = wsp;                 // 391
  int* boff   = wsp + 512;           // 391
  int* rowof  = wsp + 1024;          // 50000
  int* leafof = wsp + 1024 + GM;     // 50000
  unsigned short* Wb = (unsigned short*)((char*)d_ws + (1 << 20));  // 1 MB bf16 W

  const int nb = (CH_N + 255) / 256;   // 391

  prep_kernel<<<256 + nb, 256, 0, stream>>>(wts, Wb, children, cnt);
  scan_blocks<<<1, 512, 0, stream>>>(cnt, boff, nb);
  rank_kernel<<<nb, 256, 0, stream>>>(children, boff, CH_N, rowof, leafof);

  const float* A = x + (size_t)(PREFIX_N + LEAF_N) * CCOL;
  main_kernel<<<TILES + NCOPYB, 256, 0, stream>>>(x, A, Wb, rowof, leafof, out);
}